// Round 11
// baseline (197.558 us; speedup 1.0000x reference)
//
#include <hip/hip_runtime.h>
#include <math.h>

// ExplaiNN fused forward: B=128, N=300, L=600, K=19, C1=100, PS=7
// LC=582, LP=83, NC=2
// R27 config:
//   fills ~90us (harness re-poison, fixed poison buffer -- its own roofline)
//   kA: R18-exact FMA order + (a) ALL 20 weight float4s hoisted to regs
//       before the c-loop (last unisolated stall suspect: per-channel weight
//       load latency ~200cyc x 4, consumed 224cyc after issue; R19's prefetch
//       was confounded by rotation+copies), (b) c-loop FULLY unrolled
//       (static wreg idx, rule #20; frees scheduler to float ch c+1 s_loads
//       under ch c FMAs). VGPR ~120 -> still 4 waves/SIMD.
//       Pre-commit: kA 45.5 +/- 2us -> kA CLOSED permanently.
//   kB: absorbs kC WITHOUT fences (R17's killer was threadfence, not
//       atomics): grid 600=(n,bh), block owns all 100 h -> full fc2 sum
//       block-local -> bn3+relu local -> atomicAdd z*fw into out (pre-init
//       fb by kP). sW[83][101] (33.5KB, stride 101 -> conflict-free).
//       Kills sp traffic + kC launch + gap. unroll-8 kept (R25 WIN).
//   Falsified: fence-fusion (R17), occupancy lift (R17), c-rotation (R19),
//       per-task LDS (R20), VMEM taint +/- pipeline (R22/R26), amortized
//       LDS-x (R23/R24), s_sleep stagger (R25), 4-wave WGs, 6-wide tile.
//   XCD invariant: kA blocks-per-b % 8 == 0 (R23 broke -> 2x WRITE_SIZE).
#define EPS_ 1e-5f

// ---------------------------------------------------------------------------
// kP: cw4 pack for kA + out = fb init (graph-replay safe, runs before kB).
// ---------------------------------------------------------------------------
__global__ __launch_bounds__(256) void kP(const float* __restrict__ conv_w,
                                          float* __restrict__ cw4,
                                          const float* __restrict__ fb,
                                          float* __restrict__ out) {
    const int cq = blockIdx.x;              // 0..19
    const int c  = cq / 5;
    const int kq = cq - c * 5;
    if (cq == 0) out[threadIdx.x] = fb[threadIdx.x & 1];   // out[128][2]=fb
    for (int n = threadIdx.x; n < 300; n += 256) {
        float4 v;
        const int k0 = 4 * kq;
        v.x = (k0 + 0 < 19) ? conv_w[n * 76 + c * 19 + k0 + 0] : 0.f;
        v.y = (k0 + 1 < 19) ? conv_w[n * 76 + c * 19 + k0 + 1] : 0.f;
        v.z = (k0 + 2 < 19) ? conv_w[n * 76 + c * 19 + k0 + 2] : 0.f;
        v.w = (k0 + 3 < 19) ? conv_w[n * 76 + c * 19 + k0 + 3] : 0.f;
        reinterpret_cast<float4*>(cw4)[(c * 5 + kq) * 300 + n] = v;
    }
}

// ---------------------------------------------------------------------------
// kA: conv1d(4ch,K=19) + bias + bn1 + exp + maxpool(7,7).
// R18 structure: 2 waves/WG (subs 2i, 2i+1), grid 128*56 x 128. Persistent
// acc[4p x 7q]; x window wave-uniform -> s_loads. R27: wreg[20] weight hoist
// + full c-unroll (static indexing). FMA order R18-bit-exact.
// ---------------------------------------------------------------------------
__global__ __launch_bounds__(128) void kA(
        const float* __restrict__ x,        // [128][4][600]
        const float* __restrict__ cw4,      // [4][5][300][4]
        const float* __restrict__ conv_b,
        const float* __restrict__ g1, const float* __restrict__ b1,
        const float* __restrict__ m1, const float* __restrict__ v1,
        float* __restrict__ pooled)         // [300][83][128]
{
    const int id  = blockIdx.x;             // b*56 + i2
    const int b   = id / 56;
    const int i2  = id - b * 56;
    const int wv  = __builtin_amdgcn_readfirstlane(threadIdx.x >> 6); // 0..1
    const int sub = i2 * 2 + wv;            // 0..111
    if (sub >= 105) return;                 // wave-uniform exit
    const int ng  = sub / 21;
    const int pc  = sub - ng * 21;
    const int p0c = pc * 4;
    const int p0  = (p0c > 79) ? 79 : p0c;  // p=79 done twice, same value
    const int lane = threadIdx.x & 63;
    const int n   = ng * 64 + lane;
    const int nc  = (n < 300) ? n : 299;

    const float4* w4 = reinterpret_cast<const float4*>(cw4);

    // R27: hoist ALL weight loads; long-latency VMEM issued once, up front.
    float4 wreg[20];
    #pragma unroll
    for (int cq = 0; cq < 20; ++cq) wreg[cq] = w4[cq * 300 + nc];

    float acc[28];
    #pragma unroll
    for (int i = 0; i < 28; ++i) acc[i] = 0.f;

    #pragma unroll
    for (int c = 0; c < 4; ++c) {           // FULL unroll: static wreg idx
        const float* xc = x + b * 2400 + c * 600 + 7 * p0;  // uniform s_load
        float xw[46];
        #pragma unroll
        for (int j = 0; j < 46; ++j) xw[j] = xc[j];
        #pragma unroll
        for (int kq = 0; kq < 5; ++kq) {
            const float4 wv4 = wreg[c * 5 + kq];
            const int ni = (kq == 4) ? 3 : 4;               // k<19
            #pragma unroll
            for (int i = 0; i < ni; ++i) {
                const int k = 4 * kq + i;
                const float wvv = (i == 0) ? wv4.x : (i == 1) ? wv4.y
                                : (i == 2) ? wv4.z : wv4.w;
                #pragma unroll
                for (int p = 0; p < 4; ++p)
                    #pragma unroll
                    for (int q = 0; q < 7; ++q)
                        acc[p * 7 + q] = fmaf(xw[7 * p + q + k], wvv,
                                              acc[p * 7 + q]);
            }
        }
    }

    const float A1 = g1[nc] * rsqrtf(v1[nc] + EPS_);
    const float B1 = fmaf(A1, conv_b[nc] - m1[nc], b1[nc]);
    if (n < 300) {
        float* op = pooled + ((size_t)n * 83 + p0) * 128 + b;
        #pragma unroll
        for (int p = 0; p < 4; ++p) {
            float mx = -INFINITY;           // exp monotone: max before exp
            #pragma unroll
            for (int q = 0; q < 7; ++q)
                mx = fmaxf(mx, fmaf(A1, acc[p * 7 + q], B1));
            op[p * 128] = __expf(mx);
        }
    }
}

// ---------------------------------------------------------------------------
// kB: fc1(K=83) + bn2 + relu + fc2 + fc2b + bn3 + relu + final matmul
// contribution (absorbs kC, NO fences). grid 600 = (n, b-half), 256 thr.
// Block owns all 100 h -> full fc2 sum block-local. sW[83][101] (33.5KB,
// 101%32=5 -> conflict-free writes, broadcast reads). Waves own 25 h each.
// Final: tid<64 computes z and atomicAdds z*fw into out (pre-init fb).
// ---------------------------------------------------------------------------
__global__ __launch_bounds__(256) void kB(
        const float* __restrict__ pooled,   // [300][83][128]
        const float* __restrict__ fc1w,     // [300][100][83]
        const float* __restrict__ fc1b,     // [300][100]
        const float* __restrict__ g2, const float* __restrict__ b2,
        const float* __restrict__ m2, const float* __restrict__ v2,
        const float* __restrict__ fc2w,     // [300][100]
        const float* __restrict__ fc2b,
        const float* __restrict__ g3, const float* __restrict__ b3,
        const float* __restrict__ m3, const float* __restrict__ v3,
        const float* __restrict__ fw,       // [2][300]
        float* __restrict__ out)            // [128][2], pre-init fb
{
    __shared__ float sW[83 * 101];          // 33.5 KB
    __shared__ float sRed[4][64];
    const int id  = blockIdx.x;             // 0..599
    const int n   = id >> 1;
    const int bh  = id & 1;
    const int tid = threadIdx.x;

    {   // stage all 100 h: coalesced reads, conflict-free stride-101 writes
        const float* src = fc1w + (size_t)n * 8300;
        for (int i = tid; i < 8300; i += 256) {
            const int h = i / 83, p = i - h * 83;
            sW[p * 101 + h] = src[i];
        }
    }
    __syncthreads();

    const int lane = tid & 63;
    const int wv   = __builtin_amdgcn_readfirstlane(tid >> 6);  // 0..3
    const int h0   = wv * 25;               // 4 x 25 = 100, exact
    const int bb   = bh * 64 + lane;

    const float* pp = pooled + (size_t)n * 83 * 128 + bb;

    float acc[25];
    #pragma unroll
    for (int j = 0; j < 25; ++j) acc[j] = 0.f;

    #pragma unroll 8
    for (int p = 0; p < 83; ++p) {
        const float pv = pp[p * 128];       // coalesced 256B
        const float* wrow = sW + p * 101 + h0;
        #pragma unroll
        for (int j = 0; j < 25; ++j)        // broadcast b32 reads
            acc[j] = fmaf(wrow[j], pv, acc[j]);
    }

    // bn2 + relu + fc2 partial over this wave's 25 h's (params uniform)
    const int hbase = n * 100 + h0;
    float part = 0.f;
    #pragma unroll 5
    for (int j = 0; j < 25; ++j) {
        const int hi = hbase + j;
        const float A2 = g2[hi] * rsqrtf(v2[hi] + EPS_);
        const float C2 = fmaf(A2, fc1b[hi] - m2[hi], b2[hi]);
        part = fmaf(fmaxf(fmaf(A2, acc[j], C2), 0.f), fc2w[hi], part);
    }
    sRed[wv][lane] = part;
    __syncthreads();

    if (tid < 64) {
        const float s = sRed[0][tid] + sRed[1][tid] + sRed[2][tid]
                      + sRed[3][tid] + fc2b[n];
        const float A3 = g3[n] * rsqrtf(v3[n] + EPS_);
        const float z  = fmaxf(fmaf(A3, s - m3[n], b3[n]), 0.f);
        const int bi   = bh * 64 + tid;     // batch index
        atomicAdd(&out[bi * 2 + 0], z * fw[n]);
        atomicAdd(&out[bi * 2 + 1], z * fw[300 + n]);
    }
}

extern "C" void kernel_launch(void* const* d_in, const int* in_sizes, int n_in,
                              void* d_out, int out_size, void* d_ws, size_t ws_size,
                              hipStream_t stream) {
    const float* x      = (const float*)d_in[0];
    const float* conv_w = (const float*)d_in[1];
    const float* conv_b = (const float*)d_in[2];
    const float* g1 = (const float*)d_in[3];
    const float* b1 = (const float*)d_in[4];
    const float* m1 = (const float*)d_in[5];
    const float* v1 = (const float*)d_in[6];
    const float* fc1_w = (const float*)d_in[7];
    const float* fc1_b = (const float*)d_in[8];
    const float* g2 = (const float*)d_in[9];
    const float* b2 = (const float*)d_in[10];
    const float* m2 = (const float*)d_in[11];
    const float* v2 = (const float*)d_in[12];
    const float* fc2_w = (const float*)d_in[13];
    const float* fc2_b = (const float*)d_in[14];
    const float* g3 = (const float*)d_in[15];
    const float* b3 = (const float*)d_in[16];
    const float* m3 = (const float*)d_in[17];
    const float* v3 = (const float*)d_in[18];
    const float* fw = (const float*)d_in[19];
    const float* fb = (const float*)d_in[20];
    float* out = (float*)d_out;

    float* pooled = (float*)d_ws;                        // 300*83*128 = 3187200
    float* cw4    = pooled + (size_t)300 * 83 * 128;     // 4*5*300*4  = 24000
    // total ws: ~12.8 MB

    kP<<<20, 256, 0, stream>>>(conv_w, cw4, fb, out);
    kA<<<128 * 56, 128, 0, stream>>>(x, cw4, conv_b, g1, b1, m1, v1, pooled);
    kB<<<600, 256, 0, stream>>>(pooled, fc1_w, fc1_b, g2, b2, m2, v2,
                                fc2_w, fc2_b, g3, b3, m3, v3, fw, out);
}

// Round 12
// 179.243 us; speedup vs baseline: 1.1022x; 1.1022x over previous
//
#include <hip/hip_runtime.h>
#include <math.h>

// ExplaiNN fused forward: B=128, N=300, L=600, K=19, C1=100, PS=7
// LC=582, LP=83, NC=2
// R28 config:
//   fills ~90us (harness re-poison of fixed 256MiB poison -- own roofline)
//   kA: R18-EXACT, CLOSED at ~45.5us. Eight structural variants all
//       falsified: occupancy lift (R17 =), c-rotation (R19 v), per-task LDS
//       (R20 v), VMEM taint +/- pipeline (R22/R26 v), amortized LDS-x
//       (R23/R24 v), s_sleep stagger (R25 null), wreg hoist + full unroll
//       (R27 v, compiler refused 80-VGPR array, VALU 2x). The ~43% no-issue
//       gap is structural to this task shape on this chip.
//   kB: kC absorbed (R27 mechanism: block owns all 100 h -> fc2 sum local,
//       bn3+relu local, fence-free atomicAdd into out pre-inited by kP) at
//       R25-equal occupancy: 512 thr x grid 600 -> 18.75 waves/CU (R27's
//       256-thr version was occupancy-starved at 9.4). unroll-8 pv loop
//       (R25 WIN). sW[83][101] + zeroed pad col (wv>=4 tail reads h=100).
//   XCD invariant: kA blocks-per-b % 8 == 0 (R23 broke -> 2x WRITE_SIZE).
#define EPS_ 1e-5f

// ---------------------------------------------------------------------------
// kP: cw4 pack for kA + out = fb init (graph-replay safe, runs before kB).
// ---------------------------------------------------------------------------
__global__ __launch_bounds__(256) void kP(const float* __restrict__ conv_w,
                                          float* __restrict__ cw4,
                                          const float* __restrict__ fb,
                                          float* __restrict__ out) {
    const int cq = blockIdx.x;              // 0..19
    const int c  = cq / 5;
    const int kq = cq - c * 5;
    if (cq == 0) out[threadIdx.x] = fb[threadIdx.x & 1];   // out[128][2]=fb
    for (int n = threadIdx.x; n < 300; n += 256) {
        float4 v;
        const int k0 = 4 * kq;
        v.x = (k0 + 0 < 19) ? conv_w[n * 76 + c * 19 + k0 + 0] : 0.f;
        v.y = (k0 + 1 < 19) ? conv_w[n * 76 + c * 19 + k0 + 1] : 0.f;
        v.z = (k0 + 2 < 19) ? conv_w[n * 76 + c * 19 + k0 + 2] : 0.f;
        v.w = (k0 + 3 < 19) ? conv_w[n * 76 + c * 19 + k0 + 3] : 0.f;
        reinterpret_cast<float4*>(cw4)[(c * 5 + kq) * 300 + n] = v;
    }
}

// ---------------------------------------------------------------------------
// kA: conv1d(4ch,K=19) + bias + bn1 + exp + maxpool(7,7).  R18-EXACT
// (CLOSED): 2 waves/WG (subs 2i, 2i+1), grid 128*56 x 128. Persistent
// acc[4p x 7q]; cw4 float4 weight loads; x window wave-uniform -> s_loads.
// 56%8==0 keeps the same-XCD pooled-line mapping.
// ---------------------------------------------------------------------------
__global__ __launch_bounds__(128) void kA(
        const float* __restrict__ x,        // [128][4][600]
        const float* __restrict__ cw4,      // [4][5][300][4]
        const float* __restrict__ conv_b,
        const float* __restrict__ g1, const float* __restrict__ b1,
        const float* __restrict__ m1, const float* __restrict__ v1,
        float* __restrict__ pooled)         // [300][83][128]
{
    const int id  = blockIdx.x;             // b*56 + i2
    const int b   = id / 56;
    const int i2  = id - b * 56;
    const int wv  = __builtin_amdgcn_readfirstlane(threadIdx.x >> 6); // 0..1
    const int sub = i2 * 2 + wv;            // 0..111
    if (sub >= 105) return;                 // wave-uniform exit
    const int ng  = sub / 21;
    const int pc  = sub - ng * 21;
    const int p0c = pc * 4;
    const int p0  = (p0c > 79) ? 79 : p0c;  // p=79 done twice, same value
    const int lane = threadIdx.x & 63;
    const int n   = ng * 64 + lane;
    const int nc  = (n < 300) ? n : 299;

    const float4* w4 = reinterpret_cast<const float4*>(cw4);

    float acc[28];
    #pragma unroll
    for (int i = 0; i < 28; ++i) acc[i] = 0.f;

    #pragma unroll 1
    for (int c = 0; c < 4; ++c) {
        const float* xc = x + b * 2400 + c * 600 + 7 * p0;  // uniform -> s_load
        float xw[46];
        #pragma unroll
        for (int j = 0; j < 46; ++j) xw[j] = xc[j];
        #pragma unroll
        for (int kq = 0; kq < 5; ++kq) {
            const float4 wv4 = w4[(c * 5 + kq) * 300 + nc]; // 4 k's, coalesced
            const int ni = (kq == 4) ? 3 : 4;               // k<19
            #pragma unroll
            for (int i = 0; i < ni; ++i) {
                const int k = 4 * kq + i;
                const float wvv = (i == 0) ? wv4.x : (i == 1) ? wv4.y
                                : (i == 2) ? wv4.z : wv4.w;
                #pragma unroll
                for (int p = 0; p < 4; ++p)
                    #pragma unroll
                    for (int q = 0; q < 7; ++q)
                        acc[p * 7 + q] = fmaf(xw[7 * p + q + k], wvv,
                                              acc[p * 7 + q]);
            }
        }
    }

    const float A1 = g1[nc] * rsqrtf(v1[nc] + EPS_);
    const float B1 = fmaf(A1, conv_b[nc] - m1[nc], b1[nc]);
    if (n < 300) {
        float* op = pooled + ((size_t)n * 83 + p0) * 128 + b;
        #pragma unroll
        for (int p = 0; p < 4; ++p) {
            float mx = -INFINITY;           // exp monotone: max before exp
            #pragma unroll
            for (int q = 0; q < 7; ++q)
                mx = fmaxf(mx, fmaf(A1, acc[p * 7 + q], B1));
            op[p * 128] = __expf(mx);
        }
    }
}

// ---------------------------------------------------------------------------
// kB: fc1(K=83) + bn2 + relu + fc2 + fc2b + bn3 + relu + final matmul
// contribution (kC absorbed, fence-free). grid 600 = (n, b-half), 512 thr
// (8 waves) -> 18.75 waves/CU (R27's 256-thr was starved at 9.4).
// Block owns all 100 h -> full fc2 sum block-local. sW[83][101] (33.5KB,
// stride 101 conflict-free; pad col h=100 zeroed for the wv>=4 acc tail).
// Waves own 13/13/13/13/12/12/12/12 h. tid<64: bn3+relu+atomicAdd to out.
// ---------------------------------------------------------------------------
__global__ __launch_bounds__(512) void kB(
        const float* __restrict__ pooled,   // [300][83][128]
        const float* __restrict__ fc1w,     // [300][100][83]
        const float* __restrict__ fc1b,     // [300][100]
        const float* __restrict__ g2, const float* __restrict__ b2,
        const float* __restrict__ m2, const float* __restrict__ v2,
        const float* __restrict__ fc2w,     // [300][100]
        const float* __restrict__ fc2b,
        const float* __restrict__ g3, const float* __restrict__ b3,
        const float* __restrict__ m3, const float* __restrict__ v3,
        const float* __restrict__ fw,       // [2][300]
        float* __restrict__ out)            // [128][2], pre-init fb
{
    __shared__ float sW[83 * 101];          // 33.5 KB
    __shared__ float sRed[8][64];
    const int id  = blockIdx.x;             // 0..599
    const int n   = id >> 1;
    const int bh  = id & 1;
    const int tid = threadIdx.x;

    {   // stage all 100 h: coalesced reads, conflict-free stride-101 writes
        const float* src = fc1w + (size_t)n * 8300;
        for (int i = tid; i < 8300; i += 512) {
            const int h = i / 83, p = i - h * 83;
            sW[p * 101 + h] = src[i];
        }
        for (int i = tid; i < 83; i += 512) sW[i * 101 + 100] = 0.f; // pad col
    }
    __syncthreads();

    const int lane = tid & 63;
    const int wv   = __builtin_amdgcn_readfirstlane(tid >> 6);  // 0..7
    const int h0   = (wv < 4) ? wv * 13 : 52 + (wv - 4) * 12;
    const int nh   = (wv < 4) ? 13 : 12;    // 4*13 + 4*12 = 100
    const int bb   = bh * 64 + lane;

    const float* pp = pooled + (size_t)n * 83 * 128 + bb;

    float acc[13];
    #pragma unroll
    for (int j = 0; j < 13; ++j) acc[j] = 0.f;

    #pragma unroll 8
    for (int p = 0; p < 83; ++p) {
        const float pv = pp[p * 128];       // coalesced 256B
        const float* wrow = sW + p * 101 + h0;
        #pragma unroll
        for (int j = 0; j < 13; ++j)        // broadcast b32 reads
            acc[j] = fmaf(wrow[j], pv, acc[j]);   // j=12 @ wv>=4: pad zeros
    }

    // bn2 + relu + fc2 partial over this wave's real h's (params uniform)
    const int hbase = n * 100 + h0;
    float part = 0.f;
    for (int j = 0; j < nh; ++j) {
        const int hi = hbase + j;
        const float A2 = g2[hi] * rsqrtf(v2[hi] + EPS_);
        const float C2 = fmaf(A2, fc1b[hi] - m2[hi], b2[hi]);
        part = fmaf(fmaxf(fmaf(A2, acc[j], C2), 0.f), fc2w[hi], part);
    }
    sRed[wv][lane] = part;
    __syncthreads();

    if (tid < 64) {
        float s = fc2b[n];
        #pragma unroll
        for (int r = 0; r < 8; ++r) s += sRed[r][tid];
        const float A3 = g3[n] * rsqrtf(v3[n] + EPS_);
        const float z  = fmaxf(fmaf(A3, s - m3[n], b3[n]), 0.f);
        const int bi   = bh * 64 + tid;     // batch index
        atomicAdd(&out[bi * 2 + 0], z * fw[n]);
        atomicAdd(&out[bi * 2 + 1], z * fw[300 + n]);
    }
}

extern "C" void kernel_launch(void* const* d_in, const int* in_sizes, int n_in,
                              void* d_out, int out_size, void* d_ws, size_t ws_size,
                              hipStream_t stream) {
    const float* x      = (const float*)d_in[0];
    const float* conv_w = (const float*)d_in[1];
    const float* conv_b = (const float*)d_in[2];
    const float* g1 = (const float*)d_in[3];
    const float* b1 = (const float*)d_in[4];
    const float* m1 = (const float*)d_in[5];
    const float* v1 = (const float*)d_in[6];
    const float* fc1_w = (const float*)d_in[7];
    const float* fc1_b = (const float*)d_in[8];
    const float* g2 = (const float*)d_in[9];
    const float* b2 = (const float*)d_in[10];
    const float* m2 = (const float*)d_in[11];
    const float* v2 = (const float*)d_in[12];
    const float* fc2_w = (const float*)d_in[13];
    const float* fc2_b = (const float*)d_in[14];
    const float* g3 = (const float*)d_in[15];
    const float* b3 = (const float*)d_in[16];
    const float* m3 = (const float*)d_in[17];
    const float* v3 = (const float*)d_in[18];
    const float* fw = (const float*)d_in[19];
    const float* fb = (const float*)d_in[20];
    float* out = (float*)d_out;

    float* pooled = (float*)d_ws;                        // 300*83*128 = 3187200
    float* cw4    = pooled + (size_t)300 * 83 * 128;     // 4*5*300*4  = 24000
    // total ws: ~12.8 MB

    kP<<<20, 256, 0, stream>>>(conv_w, cw4, fb, out);
    kA<<<128 * 56, 128, 0, stream>>>(x, cw4, conv_b, g1, b1, m1, v1, pooled);
    kB<<<600, 512, 0, stream>>>(pooled, fc1_w, fc1_b, g2, b2, m2, v2,
                                fc2_w, fc2_b, g3, b3, m3, v3, fw, out);
}

// Round 13
// 174.526 us; speedup vs baseline: 1.1320x; 1.0270x over previous
//
#include <hip/hip_runtime.h>
#include <math.h>

// ExplaiNN fused forward: B=128, N=300, L=600, K=19, C1=100, PS=7
// LC=582, LP=83, NC=2
// R29 = LOCK-IN of session-best (R25's 170.4us) with the null s_sleep
// removed. Components, each at best-measured form:
//   fills ~91us: harness re-poison @ 74% HBM peak -- its own roofline.
//   kA 45.5us: R18-EXACT, CLOSED. Nine falsified variants: occupancy lift
//     (R17 =), c-rotation (R19 v), per-task LDS (R20 v), VMEM taint +/-
//     pipeline (R22/R26 v), amortized LDS-x (R23/R24 v), s_sleep stagger
//     (R25 null), wreg hoist + full unroll (R27 v, compiler refuses
//     80-VGPR arrays), 4-wave WGs / 6-wide tile / lane=b (pre-R17).
//     Structural: ~43% no-issue gap from per-channel s_load lgkm drains,
//     invariant to waves/phase/path. VALUBusy ~60% == FMA floor + epilogue.
//   kB ~9.5us: R16 split structure + R25 unroll-8 pv pipeline (WIN -3.4us).
//   kC/kP: R16-exact. kC-FUSION CLOSED: threadfence (R17 +100us),
//     256-thr fused (R27 +6us), 512-thr fused (R28 +10us) -- the ~5us
//     launch gap is cheaper than every removal mechanism tried.
//   XCD invariant: kA blocks-per-b % 8 == 0 (R23 broke -> 2x WRITE_SIZE).
#define EPS_ 1e-5f

// ---------------------------------------------------------------------------
// kP: cw4[c][kq][n][0..3] float4 conv-weight pack for kA (20 blocks, ~2us).
// ---------------------------------------------------------------------------
__global__ __launch_bounds__(256) void kP(const float* __restrict__ conv_w,
                                          float* __restrict__ cw4) {
    const int cq = blockIdx.x;              // 0..19
    const int c  = cq / 5;
    const int kq = cq - c * 5;
    for (int n = threadIdx.x; n < 300; n += 256) {
        float4 v;
        const int k0 = 4 * kq;
        v.x = (k0 + 0 < 19) ? conv_w[n * 76 + c * 19 + k0 + 0] : 0.f;
        v.y = (k0 + 1 < 19) ? conv_w[n * 76 + c * 19 + k0 + 1] : 0.f;
        v.z = (k0 + 2 < 19) ? conv_w[n * 76 + c * 19 + k0 + 2] : 0.f;
        v.w = (k0 + 3 < 19) ? conv_w[n * 76 + c * 19 + k0 + 3] : 0.f;
        reinterpret_cast<float4*>(cw4)[(c * 5 + kq) * 300 + n] = v;
    }
}

// ---------------------------------------------------------------------------
// kA: conv1d(4ch,K=19) + bias + bn1 + exp + maxpool(7,7).  R18-EXACT
// (CLOSED): 2 waves/WG (subs 2i, 2i+1), grid 128*56 x 128. Persistent
// acc[4p x 7q]; cw4 float4 weight loads; x window wave-uniform -> s_loads.
// 56%8==0 keeps the same-XCD pooled-line mapping.
// ---------------------------------------------------------------------------
__global__ __launch_bounds__(128) void kA(
        const float* __restrict__ x,        // [128][4][600]
        const float* __restrict__ cw4,      // [4][5][300][4]
        const float* __restrict__ conv_b,
        const float* __restrict__ g1, const float* __restrict__ b1,
        const float* __restrict__ m1, const float* __restrict__ v1,
        float* __restrict__ pooled)         // [300][83][128]
{
    const int id  = blockIdx.x;             // b*56 + i2
    const int b   = id / 56;
    const int i2  = id - b * 56;
    const int wv  = __builtin_amdgcn_readfirstlane(threadIdx.x >> 6); // 0..1
    const int sub = i2 * 2 + wv;            // 0..111
    if (sub >= 105) return;                 // wave-uniform exit
    const int ng  = sub / 21;
    const int pc  = sub - ng * 21;
    const int p0c = pc * 4;
    const int p0  = (p0c > 79) ? 79 : p0c;  // p=79 done twice, same value
    const int lane = threadIdx.x & 63;
    const int n   = ng * 64 + lane;
    const int nc  = (n < 300) ? n : 299;

    const float4* w4 = reinterpret_cast<const float4*>(cw4);

    float acc[28];
    #pragma unroll
    for (int i = 0; i < 28; ++i) acc[i] = 0.f;

    #pragma unroll 1
    for (int c = 0; c < 4; ++c) {
        const float* xc = x + b * 2400 + c * 600 + 7 * p0;  // uniform -> s_load
        float xw[46];
        #pragma unroll
        for (int j = 0; j < 46; ++j) xw[j] = xc[j];
        #pragma unroll
        for (int kq = 0; kq < 5; ++kq) {
            const float4 wv4 = w4[(c * 5 + kq) * 300 + nc]; // 4 k's, coalesced
            const int ni = (kq == 4) ? 3 : 4;               // k<19
            #pragma unroll
            for (int i = 0; i < ni; ++i) {
                const int k = 4 * kq + i;
                const float wvv = (i == 0) ? wv4.x : (i == 1) ? wv4.y
                                : (i == 2) ? wv4.z : wv4.w;
                #pragma unroll
                for (int p = 0; p < 4; ++p)
                    #pragma unroll
                    for (int q = 0; q < 7; ++q)
                        acc[p * 7 + q] = fmaf(xw[7 * p + q + k], wvv,
                                              acc[p * 7 + q]);
            }
        }
    }

    const float A1 = g1[nc] * rsqrtf(v1[nc] + EPS_);
    const float B1 = fmaf(A1, conv_b[nc] - m1[nc], b1[nc]);
    if (n < 300) {
        float* op = pooled + ((size_t)n * 83 + p0) * 128 + b;
        #pragma unroll
        for (int p = 0; p < 4; ++p) {
            float mx = -INFINITY;           // exp monotone: max before exp
            #pragma unroll
            for (int q = 0; q < 7; ++q)
                mx = fmaxf(mx, fmaf(A1, acc[p * 7 + q], B1));
            op[p * 128] = __expf(mx);
        }
    }
}

// ---------------------------------------------------------------------------
// kB: fc1(K=83) + bn2 + relu + fc2 partial.  R16 structure + R25 unroll-8
// (WIN): block = (n, b-half, h-half), grid 1200 x 256 -> 4.7 waves/SIMD;
// sW[83][60] staging; fc2 partials to sp; kC absorbs fc2b+bn3+relu.
// ---------------------------------------------------------------------------
__global__ __launch_bounds__(256) void kB(
        const float* __restrict__ pooled,   // [300][83][128]
        const float* __restrict__ fc1w,     // [300][100][83]
        const float* __restrict__ fc1b,     // [300][100]
        const float* __restrict__ g2, const float* __restrict__ b2,
        const float* __restrict__ m2, const float* __restrict__ v2,
        const float* __restrict__ fc2w,     // [300][100]
        float* __restrict__ sp)             // [2][300][128] fc2 partials
{
    __shared__ float sW[83 * 60];           // 19.9 KB
    __shared__ float sRed[4][64];
    const int id  = blockIdx.x;             // 0..1199
    const int n   = id >> 2;
    const int rem = id & 3;
    const int bh  = rem >> 1;
    const int hq  = rem & 1;                // h-half: h in [hq*50, hq*50+50)
    const int tid = threadIdx.x;

    {   // stage this h-half: coalesced reads; stride-60 writes (8-way, ~free)
        const float* src = fc1w + (size_t)n * 8300 + hq * 50 * 83;
        for (int i = tid; i < 4150; i += 256) {
            const int h = i / 83, p = i - h * 83;
            sW[p * 60 + h] = src[i];
        }
        for (int i = tid; i < 830; i += 256) {   // zero pad h'=50..59
            const int p = i / 10, h = 50 + (i - p * 10);
            sW[p * 60 + h] = 0.f;
        }
    }
    __syncthreads();

    const int lane = tid & 63;
    const int wv   = __builtin_amdgcn_readfirstlane(tid >> 6);  // 0..3
    const int h0   = wv * 13;               // local: 0,13,26,39
    const int nh   = (wv < 3) ? 13 : 11;    // 13*3+11 = 50
    const int bb   = bh * 64 + lane;

    const float* pp = pooled + (size_t)n * 83 * 128 + bb;

    float acc[13];
    #pragma unroll
    for (int j = 0; j < 13; ++j) acc[j] = 0.f;

    #pragma unroll 8
    for (int p = 0; p < 83; ++p) {
        const float pv = pp[p * 128];       // coalesced 256B
        const float* wrow = sW + p * 60 + h0;
        #pragma unroll
        for (int j = 0; j < 13; ++j)        // broadcast b32 reads
            acc[j] = fmaf(wrow[j], pv, acc[j]);
    }

    // bn2 + relu + fc2 partial over this wave's real h's (params uniform)
    const int hbase = n * 100 + hq * 50 + h0;
    float part = 0.f;
    for (int j = 0; j < nh; ++j) {
        const int hi = hbase + j;
        const float A2 = g2[hi] * rsqrtf(v2[hi] + EPS_);
        const float C2 = fmaf(A2, fc1b[hi] - m2[hi], b2[hi]);
        part = fmaf(fmaxf(fmaf(A2, acc[j], C2), 0.f), fc2w[hi], part);
    }
    sRed[wv][lane] = part;
    __syncthreads();

    if (tid < 64) {
        const float s = sRed[0][tid] + sRed[1][tid] + sRed[2][tid] + sRed[3][tid];
        sp[((size_t)hq * 300 + n) * 128 + bh * 64 + tid] = s;
    }
}

// ---------------------------------------------------------------------------
// kC: combine fc2 partials + fc2b + bn3 + relu, then final [300]x[2] matmul.
// ---------------------------------------------------------------------------
__global__ __launch_bounds__(64) void kC(
        const float* __restrict__ sp,       // [2][300][128]
        const float* __restrict__ fc2b,
        const float* __restrict__ g3, const float* __restrict__ b3,
        const float* __restrict__ m3, const float* __restrict__ v3,
        const float* __restrict__ fw,       // [2][300]
        const float* __restrict__ fb,
        float* __restrict__ out)            // [128][2]
{
    const int b = blockIdx.x, t = threadIdx.x;
    float a0 = 0.f, a1 = 0.f;
    for (int nn = t; nn < 300; nn += 64) {
        const float s = sp[nn * 128 + b] + sp[(300 + nn) * 128 + b] + fc2b[nn];
        const float A3 = g3[nn] * rsqrtf(v3[nn] + EPS_);
        const float z = fmaxf(fmaf(A3, s - m3[nn], b3[nn]), 0.f);
        a0 = fmaf(z, fw[nn], a0);
        a1 = fmaf(z, fw[300 + nn], a1);
    }
    #pragma unroll
    for (int off = 32; off > 0; off >>= 1) {
        a0 += __shfl_xor(a0, off, 64);
        a1 += __shfl_xor(a1, off, 64);
    }
    if (t == 0) {
        out[b * 2 + 0] = a0 + fb[0];
        out[b * 2 + 1] = a1 + fb[1];
    }
}

extern "C" void kernel_launch(void* const* d_in, const int* in_sizes, int n_in,
                              void* d_out, int out_size, void* d_ws, size_t ws_size,
                              hipStream_t stream) {
    const float* x      = (const float*)d_in[0];
    const float* conv_w = (const float*)d_in[1];
    const float* conv_b = (const float*)d_in[2];
    const float* g1 = (const float*)d_in[3];
    const float* b1 = (const float*)d_in[4];
    const float* m1 = (const float*)d_in[5];
    const float* v1 = (const float*)d_in[6];
    const float* fc1_w = (const float*)d_in[7];
    const float* fc1_b = (const float*)d_in[8];
    const float* g2 = (const float*)d_in[9];
    const float* b2 = (const float*)d_in[10];
    const float* m2 = (const float*)d_in[11];
    const float* v2 = (const float*)d_in[12];
    const float* fc2_w = (const float*)d_in[13];
    const float* fc2_b = (const float*)d_in[14];
    const float* g3 = (const float*)d_in[15];
    const float* b3 = (const float*)d_in[16];
    const float* m3 = (const float*)d_in[17];
    const float* v3 = (const float*)d_in[18];
    const float* fw = (const float*)d_in[19];
    const float* fb = (const float*)d_in[20];
    float* out = (float*)d_out;

    float* pooled = (float*)d_ws;                        // 300*83*128 = 3187200
    float* sp     = pooled + (size_t)300 * 83 * 128;     // 2*300*128  = 76800
    float* cw4    = sp + 76800;                          // 4*5*300*4  = 24000
    // total ws: ~13.2 MB

    kP<<<20, 256, 0, stream>>>(conv_w, cw4);
    kA<<<128 * 56, 128, 0, stream>>>(x, cw4, conv_b, g1, b1, m1, v1, pooled);
    kB<<<1200, 256, 0, stream>>>(pooled, fc1_w, fc1_b, g2, b2, m2, v2,
                                 fc2_w, sp);
    kC<<<128, 64, 0, stream>>>(sp, fc2_b, g3, b3, m3, v3, fw, fb, out);
}